// Round 1
// baseline (498.253 us; speedup 1.0000x reference)
//
#include <hip/hip_runtime.h>
#include <hip/hip_bf16.h>
#include <cstddef>

#define NND 94
#define NPAD 96

typedef __attribute__((ext_vector_type(8))) short sh8;
typedef __attribute__((ext_vector_type(4))) float f4v;

__device__ __forceinline__ float ftanh(float x) {
    // tanh(x) = 1 - 2/(e^{2x}+1); saturates correctly for |x| large
    float e = __expf(2.0f * x);
    return 1.0f - 2.0f / (e + 1.0f);
}

// ---------------- K0: build dense normalized A^T (padded 96x96, zeroed) ----------------
__global__ void k_prep_adj(const int* __restrict__ ei, const float* __restrict__ ew,
                           float* __restrict__ At, int E) {
    __shared__ float deg[NPAD];
    __shared__ float dinv[NPAD];
    int tid = threadIdx.x;
    for (int i = tid; i < NPAD * NPAD; i += blockDim.x) At[i] = 0.0f;
    if (tid < NPAD) deg[tid] = 0.0f;
    __syncthreads();
    for (int e = tid; e < E; e += blockDim.x)
        atomicAdd(&deg[ei[E + e]], ew[e]);
    __syncthreads();
    if (tid < NND) {
        float d = deg[tid] + 1.0f;  // self-loop weight 1.0
        dinv[tid] = d > 0.0f ? rsqrtf(d) : 0.0f;
    }
    __syncthreads();
    for (int e = tid; e < E; e += blockDim.x) {
        int s = ei[e], d = ei[E + e];
        atomicAdd(&At[s * NPAD + d], dinv[s] * ew[e] * dinv[d]);
    }
    if (tid < NND)
        atomicAdd(&At[tid * NPAD + tid], dinv[tid] * dinv[tid]);
}

// ---------------- K0b: split Wfc into bf16 hi/lo, packed in MFMA B-fragment order ----------------
// B-frag (16x16x32 bf16): lane holds B[k=(lane>>4)*8+j][n=lane&15], j=0..7
// layout: wp[((ntile*3 + kb)*64 + lane)*8 + j]
__global__ void k_pack_w(const float* __restrict__ Wfc, __hip_bfloat16* __restrict__ wp_hi,
                         __hip_bfloat16* __restrict__ wp_lo, int NOUT) {
    int t = blockIdx.x * blockDim.x + threadIdx.x;
    int total = (NOUT / 16) * 3 * 64;
    if (t >= total) return;
    int lane = t & 63;
    int kb = (t >> 6) % 3;
    int ntile = t / 192;
    int n = ntile * 16 + (lane & 15);
    int kbase = kb * 32 + ((lane >> 4) << 3);
    size_t obase = (size_t)t * 8;
#pragma unroll
    for (int j = 0; j < 8; ++j) {
        int k = kbase + j;
        float v = (k < NND) ? Wfc[(size_t)n * NND + k] : 0.0f;
        __hip_bfloat16 h = __float2bfloat16(v);
        float rem = v - __bfloat162float(h);
        wp_hi[obase + j] = h;
        wp_lo[obase + j] = __float2bfloat16(rem);
    }
}

// ---------------- K1: fused GCN (fp32) -> h2 packed in MFMA A-fragment order (bf16) ----------------
// block: 512 threads = 8 groups x 64 lanes; lane = batch within block's 64-batch tile,
// group g owns 12 node-rows. A^T rows read via wave-uniform scalar loads.
#define K1_THREADS 512
#define NR 12

__global__ void __launch_bounds__(K1_THREADS) k_gcn(
    const float* __restrict__ feat, const float* __restrict__ W1,
    const float* __restrict__ b1, const float* __restrict__ W2,
    const float* __restrict__ b2p, const float* __restrict__ At,
    __hip_bfloat16* __restrict__ h2p) {
    extern __shared__ float lds[];
    float* xs = lds;              // [282][64]  (idx = m*3+k)
    float* zs = lds + 282 * 64;   // [94][64]

    int tid = threadIdx.x;
    int lane = tid & 63;
    int g = __builtin_amdgcn_readfirstlane(tid >> 6);
    int b0 = blockIdx.x * 64;

    // preload tiny weights (uniform)
    float w1[3][6], bb1[6], w2[6];
#pragma unroll
    for (int k = 0; k < 3; ++k)
#pragma unroll
        for (int c = 0; c < 6; ++c) w1[k][c] = W1[k * 6 + c];
#pragma unroll
    for (int c = 0; c < 6; ++c) { bb1[c] = b1[c]; w2[c] = W2[c]; }
    float b2 = b2p[0];

    // stage x: xs[(m*3+k)*64 + b] = feat[b0+b][m][k]
    for (int i = tid; i < 282 * 64; i += K1_THREADS) {
        int bl = i & 63;
        int idx = i >> 6;
        xs[idx * 64 + bl] = feat[(size_t)(b0 + bl) * 282 + idx];
    }
    __syncthreads();

    int nb = g * NR;

    // phase 1: y[n][k] = sum_m At[m][n] * x[m][k]
    float y[NR][3];
#pragma unroll
    for (int i = 0; i < NR; ++i)
#pragma unroll
        for (int k = 0; k < 3; ++k) y[i][k] = 0.0f;

    for (int m = 0; m < NND; ++m) {
        float x0 = xs[(m * 3 + 0) * 64 + lane];
        float x1 = xs[(m * 3 + 1) * 64 + lane];
        float x2 = xs[(m * 3 + 2) * 64 + lane];
        const float* arow = At + m * NPAD + nb;
#pragma unroll
        for (int i = 0; i < NR; ++i) {
            float a = arow[i];
            y[i][0] += a * x0;
            y[i][1] += a * x1;
            y[i][2] += a * x2;
        }
    }

    // pointwise: z = tanh(y*W1 + b1) dot W2
#pragma unroll
    for (int i = 0; i < NR; ++i) {
        int n = nb + i;
        float z = 0.0f;
#pragma unroll
        for (int c = 0; c < 6; ++c) {
            float h = ftanh(y[i][0] * w1[0][c] + y[i][1] * w1[1][c] + y[i][2] * w1[2][c] + bb1[c]);
            z += h * w2[c];
        }
        if (n < NND) zs[n * 64 + lane] = z;
    }
    __syncthreads();

    // phase 2: s[n] = sum_m At[m][n] * z[m]
    float s[NR];
#pragma unroll
    for (int i = 0; i < NR; ++i) s[i] = 0.0f;
    for (int m = 0; m < NND; ++m) {
        float zv = zs[m * 64 + lane];
        const float* arow = At + m * NPAD + nb;
#pragma unroll
        for (int i = 0; i < NR; ++i) s[i] += arow[i] * zv;
    }

    // write h2 as bf16 in MFMA A-fragment order:
    // A-frag: lane' = (b&15) + 16*(k32>>3), element j = k32&7, tile = b>>4, kb = n>>5
    int b = b0 + lane;
    int tile = b >> 4;
    int mloc = b & 15;
#pragma unroll
    for (int i = 0; i < NR; ++i) {
        int n = nb + i;
        float h2 = (n < NND) ? ftanh(s[i] + b2) : 0.0f;
        int kb = n >> 5;
        int k32 = n & 31;
        int lp = mloc + ((k32 >> 3) << 4);
        size_t idx = ((size_t)(tile * 3 + kb) * 64 + lp) * 8 + (k32 & 7);
        h2p[idx] = __float2bfloat16(h2);
    }
}

// ---------------- K2: out[B,6400] = h2 @ Wfc^T + bfc, bf16 MFMA, Wfc hi+lo for accuracy ----------------
// block 256 = 4 waves; wave tile 64(M) x 64(N); K=96 in 3 k-blocks; no LDS.
__global__ void __launch_bounds__(256) k_gemm(
    const __hip_bfloat16* __restrict__ h2p, const __hip_bfloat16* __restrict__ wp_hi,
    const __hip_bfloat16* __restrict__ wp_lo, const float* __restrict__ bfc,
    float* __restrict__ out, int NOUT) {
    int tid = threadIdx.x;
    int lane = tid & 63;
    int wid = tid >> 6;
    int nbase = blockIdx.x * 64;
    int mbase = blockIdx.y * 256 + wid * 64;
    int mtile0 = mbase >> 4;
    int ntile0 = nbase >> 4;

    f4v acc[4][4];
#pragma unroll
    for (int mt = 0; mt < 4; ++mt)
#pragma unroll
        for (int nt = 0; nt < 4; ++nt) acc[mt][nt] = (f4v){0.0f, 0.0f, 0.0f, 0.0f};

#pragma unroll
    for (int kb = 0; kb < 3; ++kb) {
        sh8 af[4], bh[4], bl[4];
#pragma unroll
        for (int mt = 0; mt < 4; ++mt)
            af[mt] = *(const sh8*)(h2p + ((size_t)((mtile0 + mt) * 3 + kb) * 64 + lane) * 8);
#pragma unroll
        for (int nt = 0; nt < 4; ++nt) {
            size_t o = ((size_t)((ntile0 + nt) * 3 + kb) * 64 + lane) * 8;
            bh[nt] = *(const sh8*)(wp_hi + o);
            bl[nt] = *(const sh8*)(wp_lo + o);
        }
#pragma unroll
        for (int mt = 0; mt < 4; ++mt)
#pragma unroll
            for (int nt = 0; nt < 4; ++nt) {
                acc[mt][nt] = __builtin_amdgcn_mfma_f32_16x16x32_bf16(af[mt], bh[nt], acc[mt][nt], 0, 0, 0);
                acc[mt][nt] = __builtin_amdgcn_mfma_f32_16x16x32_bf16(af[mt], bl[nt], acc[mt][nt], 0, 0, 0);
            }
    }

    // epilogue: + bfc, store. C/D layout: col = lane&15, row = (lane>>4)*4 + r
    int col0 = lane & 15;
    int rowq = (lane >> 4) * 4;
    float bias[4];
#pragma unroll
    for (int nt = 0; nt < 4; ++nt) bias[nt] = bfc[nbase + nt * 16 + col0];

#pragma unroll
    for (int mt = 0; mt < 4; ++mt) {
#pragma unroll
        for (int r = 0; r < 4; ++r) {
            int row = mbase + mt * 16 + rowq + r;
            float* orow = out + (size_t)row * NOUT + nbase + col0;
#pragma unroll
            for (int nt = 0; nt < 4; ++nt)
                orow[nt * 16] = acc[mt][nt][r] + bias[nt];
        }
    }
}

extern "C" void kernel_launch(void* const* d_in, const int* in_sizes, int n_in,
                              void* d_out, int out_size, void* d_ws, size_t ws_size,
                              hipStream_t stream) {
    const float* feat = (const float*)d_in[0];
    const int*   ei   = (const int*)d_in[1];
    const float* ew   = (const float*)d_in[2];
    const float* W1   = (const float*)d_in[3];
    const float* b1   = (const float*)d_in[4];
    const float* W2   = (const float*)d_in[5];
    const float* b2   = (const float*)d_in[6];
    const float* Wfc  = (const float*)d_in[7];
    const float* bfc  = (const float*)d_in[8];
    float* out = (float*)d_out;

    int E = in_sizes[1] / 2;         // 1504
    int B = in_sizes[0] / (NND * 3); // 16384
    int NOUT = in_sizes[8];          // 6400

    // workspace carve (16B-aligned offsets)
    char* ws = (char*)d_ws;
    float* At = (float*)ws;                                        // 96*96*4 = 36864 B
    __hip_bfloat16* h2p   = (__hip_bfloat16*)(ws + 40960);         // B*96*2   = 3145728 B
    __hip_bfloat16* wp_hi = (__hip_bfloat16*)(ws + 40960 + 3145728);           // 6400*96*2
    __hip_bfloat16* wp_lo = (__hip_bfloat16*)(ws + 40960 + 3145728 + 1228800); // 6400*96*2

    k_prep_adj<<<1, 1024, 0, stream>>>(ei, ew, At, E);

    int packT = (NOUT / 16) * 3 * 64;
    k_pack_w<<<(packT + 255) / 256, 256, 0, stream>>>(Wfc, wp_hi, wp_lo, NOUT);

    size_t ldsz = (size_t)(282 * 64 + 94 * 64) * sizeof(float);  // 96256 B
    k_gcn<<<B / 64, K1_THREADS, ldsz, stream>>>(feat, W1, b1, W2, b2, At, h2p);

    dim3 g2(NOUT / 64, B / 256);
    k_gemm<<<g2, 256, 0, stream>>>(h2p, wp_hi, wp_lo, bfc, out, NOUT);
}